// Round 13
// baseline (32.994 us; speedup 1.0000x reference)
//
#include <hip/hip_runtime.h>

#define THREADS 256   // 4 waves/block
#define CPT     2     // coords per thread -> 512 blocks, 2 blocks/CU
#define NPMAX   256

typedef __attribute__((ext_vector_type(16))) float f32x16;
typedef __attribute__((ext_vector_type(2)))  float f32x2;

static __device__ __forceinline__ f32x2 fmav(f32x2 a, f32x2 b, f32x2 c) {
    return __builtin_elementwise_fma(a, b, c);   // -> v_pk_fma_f32
}

// consecutive SGPR pair (2k,2k+1) of the pre-duplicated constant vector:
// a ready-made 64-bit packed operand {v,v} for VOP3P (1 scalar read rule ok)
#define PK(V, k) (__builtin_shufflevector((V), (V), (2 * (k)), (2 * (k) + 1)))

#define SLOAD16_0(dst, base) \
    asm volatile("s_load_dwordx16 %0, %1, 0x0"  : "=s"(dst) : "s"(base))
#define SLOAD16_64(dst, base) \
    asm volatile("s_load_dwordx16 %0, %1, 0x40" : "=s"(dst) : "s"(base))
#define SWAIT0() do { \
    asm volatile("s_waitcnt lgkmcnt(0)" ::: "memory"); \
    __builtin_amdgcn_sched_barrier(0); \
} while (0)

// one particle (pre-dup layout {px,px,py,py,pz,pz,cw,cw,bx,bx,by,by,bz,bz,bw,bw})
// against the packed coord pair; every pk op reads <=1 scalar operand.
#define INTER2(V) { \
    f32x2 lx = PK(V,0) - cxv; \
    f32x2 ly = PK(V,1) - cyv; \
    f32x2 lz = PK(V,2) - czv; \
    f32x2 d2 = fmav(lx, lx, fmav(ly, ly, lz * lz)); \
    f32x2 arg = d2 * PK(V,3); \
    float s0 = __builtin_amdgcn_exp2f(arg.x) * __builtin_amdgcn_rsqf(d2.x); \
    float s1 = __builtin_amdgcn_exp2f(arg.y) * __builtin_amdgcn_rsqf(d2.y); \
    f32x2 s; \
    s.x = (d2.x < V[14]) ? s0 : 0.0f; \
    s.y = (d2.y < V[14]) ? s1 : 0.0f; \
    f32x2 crx = fmav(ly, PK(V,6), -(lz * PK(V,5))); \
    f32x2 cry = fmav(lz, PK(V,4), -(lx * PK(V,6))); \
    f32x2 crz = fmav(lx, PK(V,5), -(ly * PK(V,4))); \
    axv = fmav(s, crx, axv); \
    ayv = fmav(s, cry, ayv); \
    azv = fmav(s, crz, azv); \
}

// ---------------------------------------------------------------------------
// Prep (1 block): per-particle constants at time_idx, ballot-compacted
// (deterministic stable order), written PRE-DUPLICATED (16 floats/particle),
// zero-padded to a multiple of 4 (pad: bw=0 -> d2<0 never -> exact 0).
// ---------------------------------------------------------------------------
__global__ __launch_bounds__(THREADS) void vortex_prep(
        const float* __restrict__ ppos,
        const float* __restrict__ pdir,
        const float* __restrict__ pint,
        const float* __restrict__ iraw,
        const float* __restrict__ rad,
        const int*   __restrict__ tmask,
        const int*   __restrict__ tidxp,
        int P, int T,
        float* __restrict__ pdup,
        int*   __restrict__ dcount) {
    __shared__ int wtot[THREADS / 64];
    const int tid  = threadIdx.x;
    const int lane = tid & 63;
    const int wid  = tid >> 6;
    const int t = *tidxp;

    bool active = false;
    float4 a, b;
    if (tid < P) {
        const int p = tid;
        float m  = (float)tmask[p * T + t];
        float cl = fminf(fmaxf(iraw[p], 0.0f), 10.0f);
        float w  = sqrtf(cl + 1e-8f) * pint[p * T + t] * m;
        float r  = fmaxf(0.2f * (0.5f * rad[p] + 1.0f), 0.0f);
        active   = (w != 0.0f) && (r > 0.0f);
        if (active) {
            const float* pp = ppos + (size_t)(p * T + t) * 3;
            const float* pd = pdir + (size_t)(p * T + t) * 3;
            float A = w / (r * r * r * 40000.0f);
            a = make_float4(pp[0], pp[1], pp[2], -1.442695040888963f / (2.0f * r * r));
            b = make_float4(A * pd[0], A * pd[1], A * pd[2], 9.0f * r * r);
        }
    }
    unsigned long long bm = __ballot(active);
    int pre = __popcll(bm & ((1ull << lane) - 1ull));
    if (lane == 0) wtot[wid] = __popcll(bm);
    __syncthreads();
    int off = 0, tot = 0;
    #pragma unroll
    for (int w2 = 0; w2 < THREADS / 64; ++w2) {
        int c = wtot[w2];
        if (w2 < wid) off += c;
        tot += c;
    }
    if (active) {
        float4* q = (float4*)(pdup + (size_t)(off + pre) * 16);
        q[0] = make_float4(a.x, a.x, a.y, a.y);
        q[1] = make_float4(a.z, a.z, a.w, a.w);
        q[2] = make_float4(b.x, b.x, b.y, b.y);
        q[3] = make_float4(b.z, b.z, b.w, b.w);
    }
    const int tot_pad = (tot + 3) & ~3;
    if (tid >= tot && tid < tot_pad) {
        float4* q = (float4*)(pdup + (size_t)tid * 16);
        float4 z = make_float4(0.f, 0.f, 0.f, 0.f);
        q[0] = z; q[1] = z; q[2] = z; q[3] = z;
    }
    if (tid == 0) *dcount = tot_pad;
}

// ---------------------------------------------------------------------------
// Main: packed-fp32 inner loop (CPT=2); particle constants via double-buffered
// s_load_dwordx16 into SGPRs (batch = 2 particles, lgkmcnt(0) per batch since
// SMEM returns out-of-order; the in-flight batch hides under the other
// batch's compute). No LDS, no vector memory in the hot loop.
// ---------------------------------------------------------------------------
__global__ __launch_bounds__(THREADS) void vortex_main(
        const float* __restrict__ coord,
        const float* __restrict__ parts,     // pre-dup, 16 floats/particle
        const int*   __restrict__ dcount,
        float*       __restrict__ out,
        int N) {
    const int tid = threadIdx.x;
    const int i0 = blockIdx.x * (THREADS * CPT) + tid;
    const int i1 = i0 + THREADS;
    const bool v0 = (i0 < N), v1 = (i1 < N);

    f32x2 cxv, cyv, czv;
    cxv.x = cxv.y = cyv.x = cyv.y = czv.x = czv.y = 0.f;
    if (v0) { cxv.x = coord[3 * i0]; cyv.x = coord[3 * i0 + 1]; czv.x = coord[3 * i0 + 2]; }
    if (v1) { cxv.y = coord[3 * i1]; cyv.y = coord[3 * i1 + 1]; czv.y = coord[3 * i1 + 2]; }

    const int cnt = __builtin_amdgcn_readfirstlane(*dcount);   // multiple of 4

    f32x2 axv, ayv, azv;
    axv.x = axv.y = ayv.x = ayv.y = azv.x = azv.y = 0.f;

    if (cnt > 0) {
        const float* bp = parts;
        f32x16 A0, A1, B0, B1;
        SLOAD16_0(A0, bp);
        SLOAD16_64(A1, bp);
        for (int p = 0; p < cnt; p += 4) {
            const float* bpB = bp + 32;                          // particles p+2,p+3
            const float* bpN = (p + 4 < cnt) ? bp + 64 : parts;  // next round (dummy at end)
            SWAIT0();                       // A0,A1 ready
            SLOAD16_0(B0, bpB);
            SLOAD16_64(B1, bpB);
            INTER2(A0);
            INTER2(A1);
            SWAIT0();                       // B0,B1 ready (flew under A compute)
            SLOAD16_0(A0, bpN);
            SLOAD16_64(A1, bpN);
            INTER2(B0);
            INTER2(B1);
            bp += 64;
        }
    }

    if (v0) { out[3 * i0] = axv.x; out[3 * i0 + 1] = ayv.x; out[3 * i0 + 2] = azv.x; }
    if (v1) { out[3 * i1] = axv.y; out[3 * i1 + 1] = ayv.y; out[3 * i1 + 2] = azv.y; }
}

extern "C" void kernel_launch(void* const* d_in, const int* in_sizes, int n_in,
                              void* d_out, int out_size, void* d_ws, size_t ws_size,
                              hipStream_t stream) {
    const float* coord = (const float*)d_in[0];
    const float* ppos  = (const float*)d_in[1];
    const float* pdir  = (const float*)d_in[2];
    const float* pint  = (const float*)d_in[3];
    const float* iraw  = (const float*)d_in[4];
    const float* rad   = (const float*)d_in[5];
    const int*   tmask = (const int*)d_in[6];
    const int*   tidx  = (const int*)d_in[7];
    float* out = (float*)d_out;

    const int N = in_sizes[0] / 3;        // 262144 coords
    const int P = in_sizes[4];            // 256 particles
    const int T = in_sizes[3] / P;        // 8 time steps

    float* pdup = (float*)d_ws;                                   // 16 KB
    int* dcount = (int*)((char*)d_ws + (size_t)NPMAX * 16 * sizeof(float));

    hipLaunchKernelGGL(vortex_prep, dim3(1), dim3(THREADS), 0, stream,
                       ppos, pdir, pint, iraw, rad, tmask, tidx, P, T, pdup, dcount);

    const int coordsPerBlock = THREADS * CPT;
    const int blocks = (N + coordsPerBlock - 1) / coordsPerBlock;
    hipLaunchKernelGGL(vortex_main, dim3(blocks), dim3(THREADS), 0, stream,
                       coord, pdup, dcount, out, N);
}

// Round 14
// 25.867 us; speedup vs baseline: 1.2755x; 1.2755x over previous
//
#include <hip/hip_runtime.h>

#define THREADS 256   // 4 waves/block
#define CPT     4     // coords per thread -> 256 blocks, 1 wave/SIMD
#define NPMAX   256   // max particles

typedef __attribute__((ext_vector_type(2))) float f32x2;

static __device__ __forceinline__ f32x2 v2(float v) { f32x2 r; r.x = v; r.y = v; return r; }
static __device__ __forceinline__ f32x2 fmav(f32x2 a, f32x2 b, f32x2 c) {
    return __builtin_elementwise_fma(a, b, c);   // -> v_pk_fma_f32
}

// one particle (pa,pb) against both packed coord groups
#define INTER4(pa, pb) { \
    { \
        f32x2 lx = v2(pa.x) - cxA, ly = v2(pa.y) - cyA, lz = v2(pa.z) - czA; \
        f32x2 d2 = fmav(lx, lx, fmav(ly, ly, lz * lz)); \
        f32x2 arg = d2 * v2(pa.w); \
        f32x2 s; \
        s.x = __builtin_amdgcn_exp2f(arg.x) * __builtin_amdgcn_rsqf(d2.x); \
        s.y = __builtin_amdgcn_exp2f(arg.y) * __builtin_amdgcn_rsqf(d2.y); \
        s.x = (d2.x < pb.w) ? s.x : 0.0f; \
        s.y = (d2.y < pb.w) ? s.y : 0.0f; \
        f32x2 crx = fmav(ly, v2(pb.z), -(lz * v2(pb.y))); \
        f32x2 cry = fmav(lz, v2(pb.x), -(lx * v2(pb.z))); \
        f32x2 crz = fmav(lx, v2(pb.y), -(ly * v2(pb.x))); \
        axA = fmav(s, crx, axA); ayA = fmav(s, cry, ayA); azA = fmav(s, crz, azA); \
    } \
    { \
        f32x2 lx = v2(pa.x) - cxB, ly = v2(pa.y) - cyB, lz = v2(pa.z) - czB; \
        f32x2 d2 = fmav(lx, lx, fmav(ly, ly, lz * lz)); \
        f32x2 arg = d2 * v2(pa.w); \
        f32x2 s; \
        s.x = __builtin_amdgcn_exp2f(arg.x) * __builtin_amdgcn_rsqf(d2.x); \
        s.y = __builtin_amdgcn_exp2f(arg.y) * __builtin_amdgcn_rsqf(d2.y); \
        s.x = (d2.x < pb.w) ? s.x : 0.0f; \
        s.y = (d2.y < pb.w) ? s.y : 0.0f; \
        f32x2 crx = fmav(ly, v2(pb.z), -(lz * v2(pb.y))); \
        f32x2 cry = fmav(lz, v2(pb.x), -(lx * v2(pb.z))); \
        f32x2 crz = fmav(lx, v2(pb.y), -(ly * v2(pb.x))); \
        axB = fmav(s, crx, axB); ayB = fmav(s, cry, ayB); azB = fmav(s, crz, azB); \
    } \
}

// ---------------------------------------------------------------------------
// Fused kernel: packed fp32, CPT=4 (2 LDS reads serve 4 coords), with an
// EXPLICIT 1-iteration (2-particle) register prefetch pipeline so ds_read
// latency hides under the previous pair's ~300 cyc of pk-FMA/trans work
// (1 wave/SIMD has no co-wave to cover exposed LDS waits).
// Constants: pa = {px,py,pz, -log2e/(2r^2)}, pb = {A*dx,A*dy,A*dz, 9r^2}.
// cnt is zero-padded to a multiple of 2 (pads contribute exactly 0).
// ---------------------------------------------------------------------------
__global__ __launch_bounds__(THREADS) void vortex_fused(
        const float* __restrict__ coord,
        const float* __restrict__ ppos,
        const float* __restrict__ pdir,
        const float* __restrict__ pint,
        const float* __restrict__ iraw,
        const float* __restrict__ rad,
        const int*   __restrict__ tmask,
        const int*   __restrict__ tidxp,
        float*       __restrict__ out,
        int N, int P, int T) {
    __shared__ float4 sp[2 * NPMAX + 4];
    __shared__ int    wtot[THREADS / 64];
    __shared__ int    s_cnt;

    const int tid  = threadIdx.x;
    const int lane = tid & 63;
    const int wid  = tid >> 6;

    // ---- coord loads first so they overlap the prep work ----
    const int i0 = blockIdx.x * (THREADS * CPT) + tid;
    const int i1 = i0 + THREADS;
    const int i2 = i0 + 2 * THREADS;
    const int i3 = i0 + 3 * THREADS;
    const bool v0 = (i0 < N), v1 = (i1 < N), v2_ = (i2 < N), v3 = (i3 < N);
    f32x2 cxA = v2(0.f), cyA = v2(0.f), czA = v2(0.f);   // coords 0,1
    f32x2 cxB = v2(0.f), cyB = v2(0.f), czB = v2(0.f);   // coords 2,3
    if (v0) { cxA.x = coord[3 * i0]; cyA.x = coord[3 * i0 + 1]; czA.x = coord[3 * i0 + 2]; }
    if (v1) { cxA.y = coord[3 * i1]; cyA.y = coord[3 * i1 + 1]; czA.y = coord[3 * i1 + 2]; }
    if (v2_) { cxB.x = coord[3 * i2]; cyB.x = coord[3 * i2 + 1]; czB.x = coord[3 * i2 + 2]; }
    if (v3) { cxB.y = coord[3 * i3]; cyB.y = coord[3 * i3 + 1]; czB.y = coord[3 * i3 + 2]; }

    // ---- per-particle prep + ballot compaction (deterministic order) ----
    const int t = *tidxp;
    bool active = false;
    float4 a, b;
    if (tid < P) {
        const int p = tid;
        float m  = (float)tmask[p * T + t];
        float cl = fminf(fmaxf(iraw[p], 0.0f), 10.0f);
        float w  = sqrtf(cl + 1e-8f) * pint[p * T + t] * m;
        float r  = fmaxf(0.2f * (0.5f * rad[p] + 1.0f), 0.0f);
        active   = (w != 0.0f) && (r > 0.0f);
        if (active) {
            const float* pp = ppos + (size_t)(p * T + t) * 3;
            const float* pd = pdir + (size_t)(p * T + t) * 3;
            float A = w / (r * r * r * 40000.0f);
            a = make_float4(pp[0], pp[1], pp[2], -1.442695040888963f / (2.0f * r * r));
            b = make_float4(A * pd[0], A * pd[1], A * pd[2], 9.0f * r * r);
        }
    }
    unsigned long long bm = __ballot(active);
    int pre = __popcll(bm & ((1ull << lane) - 1ull));
    if (lane == 0) wtot[wid] = __popcll(bm);
    __syncthreads();
    int off = 0, tot = 0;
    #pragma unroll
    for (int w2 = 0; w2 < THREADS / 64; ++w2) {
        int c = wtot[w2];
        if (w2 < wid) off += c;
        tot += c;
    }
    if (active) {
        int pos = off + pre;
        sp[2 * pos]     = a;
        sp[2 * pos + 1] = b;
    }
    // zero-pad to multiple of 2 (pb.w = 0 -> d2 < 0 never true -> exact 0)
    const int tot_pad = (tot + 1) & ~1;
    if (tid >= tot && tid < tot_pad) {
        float4 z = make_float4(0.f, 0.f, 0.f, 0.f);
        sp[2 * tid]     = z;
        sp[2 * tid + 1] = z;
    }
    if (tid == 0) s_cnt = tot_pad;
    __syncthreads();
    const int cnt = s_cnt;   // uniform, multiple of 2

    // ---- packed main loop with 2-particle register rotation ----
    f32x2 axA = v2(0.f), ayA = v2(0.f), azA = v2(0.f);
    f32x2 axB = v2(0.f), ayB = v2(0.f), azB = v2(0.f);

    float4 pa0 = sp[0], pb0 = sp[1], pa1 = sp[2], pb1 = sp[3];
    for (int p = 0; p < cnt; p += 2) {
        const int q = (p + 2 < cnt) ? (p + 2) : 0;   // prefetch next pair
        float4 na0 = sp[2 * q];
        float4 nb0 = sp[2 * q + 1];
        float4 na1 = sp[2 * q + 2];
        float4 nb1 = sp[2 * q + 3];
        INTER4(pa0, pb0);
        INTER4(pa1, pb1);
        pa0 = na0; pb0 = nb0; pa1 = na1; pb1 = nb1;
    }

    if (v0) { out[3 * i0] = axA.x; out[3 * i0 + 1] = ayA.x; out[3 * i0 + 2] = azA.x; }
    if (v1) { out[3 * i1] = axA.y; out[3 * i1 + 1] = ayA.y; out[3 * i1 + 2] = azA.y; }
    if (v2_) { out[3 * i2] = axB.x; out[3 * i2 + 1] = ayB.x; out[3 * i2 + 2] = azB.x; }
    if (v3) { out[3 * i3] = axB.y; out[3 * i3 + 1] = ayB.y; out[3 * i3 + 2] = azB.y; }
}

extern "C" void kernel_launch(void* const* d_in, const int* in_sizes, int n_in,
                              void* d_out, int out_size, void* d_ws, size_t ws_size,
                              hipStream_t stream) {
    const float* coord = (const float*)d_in[0];
    const float* ppos  = (const float*)d_in[1];
    const float* pdir  = (const float*)d_in[2];
    const float* pint  = (const float*)d_in[3];
    const float* iraw  = (const float*)d_in[4];
    const float* rad   = (const float*)d_in[5];
    const int*   tmask = (const int*)d_in[6];
    const int*   tidx  = (const int*)d_in[7];
    float* out = (float*)d_out;

    const int N = in_sizes[0] / 3;        // 262144 coords
    const int P = in_sizes[4];            // 256 particles (intensity_raw is (P,1))
    const int T = in_sizes[3] / P;        // 8 time steps (particle_intensity is (P,T,1))

    const int coordsPerBlock = THREADS * CPT;
    const int blocks = (N + coordsPerBlock - 1) / coordsPerBlock;
    hipLaunchKernelGGL(vortex_fused, dim3(blocks), dim3(THREADS), 0, stream,
                       coord, ppos, pdir, pint, iraw, rad, tmask, tidx, out, N, P, T);
}